// Round 1
// baseline (33.463 us; speedup 1.0000x reference)
//
#include <hip/hip_runtime.h>

// Output: (B=32, L+2=1026, O*D=1024) f32.
// Row semantics: p==0 -> 1.0; 1<=p<=len -> x[b,p-1,:]*softmax(w)[c/256];
//                p==len+1 -> 2.0; else 0.0.
// One block per output row; thread t handles float4 #t of the row.

__global__ __launch_bounds__(256) void MixedOp_kernel(
    const float* __restrict__ x,        // (32,1024,4,256) contiguous
    const float* __restrict__ weights,  // (4,)
    const int* __restrict__ lengths,    // (32,)
    float* __restrict__ out)            // (32,1026,1024)
{
    constexpr int L    = 1024;
    constexpr int LP2  = 1026;
    constexpr int ROW4 = 256;   // float4 per row (O*D/4)

    const int row = blockIdx.x;          // 0 .. 32*1026-1
    const int b   = row / LP2;
    const int p   = row - b * LP2;       // 0 .. 1025
    const int c4  = threadIdx.x;         // 0 .. 255

    const int len = lengths[b];

    float4 v;
    if (p == 0) {
        v = make_float4(1.f, 1.f, 1.f, 1.f);
    } else if (p <= len) {
        // softmax over 4 weights (cheap, L1-cached)
        const float w0 = weights[0], w1 = weights[1], w2 = weights[2], w3 = weights[3];
        const float m  = fmaxf(fmaxf(w0, w1), fmaxf(w2, w3));
        const float e0 = expf(w0 - m), e1 = expf(w1 - m),
                    e2 = expf(w2 - m), e3 = expf(w3 - m);
        const float inv = 1.0f / (e0 + e1 + e2 + e3);
        const float wsm[4] = { e0 * inv, e1 * inv, e2 * inv, e3 * inv };

        const float4* __restrict__ xv = reinterpret_cast<const float4*>(x);
        const size_t xidx = (size_t)b * (L * ROW4) + (size_t)(p - 1) * ROW4 + c4;
        const float4 xx = xv[xidx];
        const float wo = wsm[c4 >> 6];   // c4/64: which of the 4 O-chunks
        v = make_float4(xx.x * wo, xx.y * wo, xx.z * wo, xx.w * wo);
    } else if (p == len + 1) {
        v = make_float4(2.f, 2.f, 2.f, 2.f);
    } else {
        v = make_float4(0.f, 0.f, 0.f, 0.f);
    }

    reinterpret_cast<float4*>(out)[(size_t)row * ROW4 + c4] = v;
}

extern "C" void kernel_launch(void* const* d_in, const int* in_sizes, int n_in,
                              void* d_out, int out_size, void* d_ws, size_t ws_size,
                              hipStream_t stream) {
    const float* x       = (const float*)d_in[0];
    const float* weights = (const float*)d_in[1];
    const int*   lengths = (const int*)d_in[2];
    float*       out     = (float*)d_out;

    constexpr int B = 32, LP2 = 1026;
    dim3 grid(B * LP2);
    dim3 block(256);
    MixedOp_kernel<<<grid, block, 0, stream>>>(x, weights, lengths, out);
}